// Round 1
// baseline (649.686 us; speedup 1.0000x reference)
//
#include <hip/hip_runtime.h>

typedef __bf16 bf16;
typedef float  f32x4  __attribute__((ext_vector_type(4)));
typedef float  f32x2  __attribute__((ext_vector_type(2)));
typedef __bf16 bf16x8 __attribute__((ext_vector_type(8)));
typedef __bf16 bf16x4 __attribute__((ext_vector_type(4)));
typedef unsigned short ushort4_ __attribute__((ext_vector_type(4)));

typedef unsigned int __attribute__((address_space(1))) uint_g;
typedef unsigned int __attribute__((address_space(3))) uint_l;

#define DEV __device__ __forceinline__

DEV void gload16(const void* g, void* l) {
  // async global->LDS, 16B per lane; LDS dst is wave-uniform base + lane*16
  __builtin_amdgcn_global_load_lds((uint_g*)g, (uint_l*)l, 16, 0, 0);
}

// ---------------- fp32 -> bf16 convert (vectorized) ----------------
__global__ void k_cvt(const float* __restrict__ in, bf16* __restrict__ out) {
  int i = blockIdx.x * 256 + threadIdx.x;          // one float4 per thread
  f32x4 v = *((const f32x4*)in + i);
  bf16x4 o;
  o[0] = (bf16)v[0]; o[1] = (bf16)v[1]; o[2] = (bf16)v[2]; o[3] = (bf16)v[3];
  *((bf16x4*)out + i) = o;
}

// ---------------- [K][N] fp32 -> [N][K] bf16 transpose ----------------
__global__ void k_transpose_cvt(const float* __restrict__ in, bf16* __restrict__ out,
                                int K, int N) {
  __shared__ bf16 tile[64][65];
  int n0 = blockIdx.x * 64, k0 = blockIdx.y * 64;
  int tx = threadIdx.x & 63, ty = threadIdx.x >> 6;
#pragma unroll
  for (int r = 0; r < 64; r += 4)
    tile[r + ty][tx] = (bf16)in[(size_t)(k0 + r + ty) * N + n0 + tx];
  __syncthreads();
#pragma unroll
  for (int r = 0; r < 64; r += 4)
    out[(size_t)(n0 + r + ty) * K + k0 + tx] = tile[tx][r + ty];
}

// ---------------- RoPE cos/sin table: [T][64] of (cos,sin) ----------------
__global__ void k_rope_tab(f32x2* __restrict__ tab) {
  int idx = blockIdx.x * 256 + threadIdx.x;   // T*64
  int t = idx >> 6, i = idx & 63;
  float inv = powf(10000.f, -(float)i * (1.f / 64.f));
  float ang = (float)t * inv;
  f32x2 cs; cs[0] = cosf(ang); cs[1] = sinf(ang);
  tab[idx] = cs;
}

// ---------------- m97-style GEMM: C = A @ Bt^T ----------------
// A [M][K] bf16 row-major, Bt [N][K] bf16 row-major.
// MODE 0: C fp32 [M][N]. MODE 1: C bf16 [M][N].
// MODE 2: C bf16 V-transpose: out[b][kv][d][t] with row=b*2048+t, col=kv*128+d.
template <int MODE>
__global__ __launch_bounds__(256) void k_gemm(const bf16* __restrict__ A,
                                              const bf16* __restrict__ Bt,
                                              void* __restrict__ C,
                                              int M, int N, int K) {
  __shared__ bf16 As[128 * 32];
  __shared__ bf16 Bs[128 * 32];
  const int tid = threadIdx.x;
  const int w = tid >> 6, l = tid & 63;
  const int bm = blockIdx.y, bn = blockIdx.x;
  const int wr = w >> 1, wc = w & 1;
  const int lr = l & 15, lg = l >> 4;

  const bf16* ag = A  + (size_t)(bm * 128 + w * 16 + (l >> 2)) * K + (l & 3) * 8;
  const bf16* bg = Bt + (size_t)(bn * 128 + w * 16 + (l >> 2)) * K + (l & 3) * 8;
  bf16* as0 = &As[w * 512];
  bf16* as1 = &As[64 * 32 + w * 512];
  bf16* bs0 = &Bs[w * 512];
  bf16* bs1 = &Bs[64 * 32 + w * 512];
  const size_t astep = (size_t)64 * K;

  f32x4 acc[4][4] = {};

  for (int k0 = 0; k0 < K; k0 += 32) {
    __syncthreads();
    gload16(ag, as0);
    gload16(ag + astep, as1);
    gload16(bg, bs0);
    gload16(bg + astep, bs1);
    ag += 32; bg += 32;
    __syncthreads();
    bf16x8 af[4], bfr[4];
#pragma unroll
    for (int m = 0; m < 4; m++)
      af[m] = *(const bf16x8*)&As[(wr * 64 + m * 16 + lr) * 32 + lg * 8];
#pragma unroll
    for (int n = 0; n < 4; n++)
      bfr[n] = *(const bf16x8*)&Bs[(wc * 64 + n * 16 + lr) * 32 + lg * 8];
#pragma unroll
    for (int m = 0; m < 4; m++)
#pragma unroll
      for (int n = 0; n < 4; n++)
        acc[m][n] = __builtin_amdgcn_mfma_f32_16x16x32_bf16(af[m], bfr[n], acc[m][n], 0, 0, 0);
  }

  const int row0 = bm * 128 + wr * 64;
  const int col0 = bn * 128 + wc * 64;
#pragma unroll
  for (int m = 0; m < 4; m++) {
#pragma unroll
    for (int n = 0; n < 4; n++) {
      int col = col0 + n * 16 + lr;
      if constexpr (MODE == 0) {
        float* Cf = (float*)C;
#pragma unroll
        for (int j = 0; j < 4; j++) {
          int row = row0 + m * 16 + lg * 4 + j;
          Cf[(size_t)row * N + col] = acc[m][n][j];
        }
      } else if constexpr (MODE == 1) {
        bf16* Cb = (bf16*)C;
#pragma unroll
        for (int j = 0; j < 4; j++) {
          int row = row0 + m * 16 + lg * 4 + j;
          Cb[(size_t)row * N + col] = (bf16)acc[m][n][j];
        }
      } else {
        bf16* Cb = (bf16*)C;
        int rowb = row0 + m * 16 + lg * 4;        // 4 consecutive tokens
        int bb = rowb >> 11, t0 = rowb & 2047;
        size_t off = ((size_t)((bb * 4 + (col >> 7)) * 128 + (col & 127))) * 2048 + t0;
        ushort4_ pk;
#pragma unroll
        for (int j = 0; j < 4; j++)
          pk[j] = __builtin_bit_cast(unsigned short, (bf16)acc[m][n][j]);
        *(ushort4_*)(Cb + off) = pk;
      }
    }
  }
}

// ---------------- RoPE + rearrange: [B*T][NH*128] -> [B][NH][T][128] ----------------
template <int LOGNH>
__global__ void k_rope(const bf16* __restrict__ in, bf16* __restrict__ out,
                       const f32x2* __restrict__ tab) {
  const int NH = 1 << LOGNH;
  int idx = blockIdx.x * 256 + threadIdx.x;
  int dq = idx & 15;                        // d0 = dq*4
  int h = (idx >> 4) & (NH - 1);
  int bt = idx >> (4 + LOGNH);
  int t = bt & 2047;
  int d0 = dq * 4;
  const bf16* pin = in + (size_t)bt * (NH * 128) + h * 128;
  bf16x4 x1 = *(const bf16x4*)(pin + d0);
  bf16x4 x2 = *(const bf16x4*)(pin + 64 + d0);
  bf16x4 o1, o2;
#pragma unroll
  for (int j = 0; j < 4; j++) {
    f32x2 cs = tab[t * 64 + d0 + j];
    float a = (float)x1[j], c2 = (float)x2[j];
    o1[j] = (bf16)(a * cs[0] - c2 * cs[1]);
    o2[j] = (bf16)(c2 * cs[0] + a * cs[1]);
  }
  int b = bt >> 11;
  bf16* pout = out + (((size_t)(b << LOGNH) + h) * 2048 + t) * 128;
  *(bf16x4*)(pout + d0) = o1;
  *(bf16x4*)(pout + 64 + d0) = o2;
}

// ---------------- flash attention (causal, GQA) ----------------
// Qb [B][16][T][128], Kb [B][4][T][128] (rope'd), Vt [B][4][128][T], AO [B*T][2048]
__global__ __launch_bounds__(256) void k_attn(const bf16* __restrict__ Qb,
                                              const bf16* __restrict__ Kb,
                                              const bf16* __restrict__ Vt,
                                              bf16* __restrict__ AO) {
  __shared__ bf16 Ks[64 * 128];   // [kv 64][d 128], XOR-swizzled rows
  __shared__ bf16 Vs[128 * 64];   // [d 128][kv 64], XOR-swizzled rows
  __shared__ bf16 Ps[4][16 * 64]; // per-wave P tile, swizzled
  const int tid = threadIdx.x, w = tid >> 6, l = tid & 63;
  const int bh = blockIdx.y, b = bh >> 4, h = bh & 15, kvh = h >> 2;
  const int q0 = blockIdx.x * 64;
  const int lr = l & 15, lg = l >> 4;
  const float scale = 0.08838834764831845f;

  bf16x8 qf[4];
  {
    const bf16* qp = Qb + (((size_t)(b * 16 + h) * 2048) + q0 + w * 16 + lr) * 128 + lg * 8;
#pragma unroll
    for (int kk = 0; kk < 4; kk++) qf[kk] = *(const bf16x8*)(qp + kk * 32);
  }
  const bf16* Kh = Kb + (size_t)(b * 4 + kvh) * (2048 * 128);
  const bf16* Vh = Vt + (size_t)(b * 4 + kvh) * (128 * 2048);

  f32x4 o[8] = {};
  float mrun[4], lrun[4];
#pragma unroll
  for (int j = 0; j < 4; j++) { mrun[j] = -1e30f; lrun[j] = 0.f; }

  for (int kv0 = 0; kv0 <= q0; kv0 += 64) {
    __syncthreads();
    // stage K[kv0:kv0+64][0:128] and Vt[0:128][kv0:kv0+64], source pre-swizzled
#pragma unroll
    for (int i = 0; i < 4; i++) {
      int krow = w * 16 + i * 4 + lg;
      int kcb = ((l & 15) * 16) ^ ((krow & 7) << 4);
      gload16(Kh + (size_t)(kv0 + krow) * 128 + (kcb >> 1), &Ks[w * 2048 + i * 512]);
      int vrow = w * 32 + i * 8 + (l >> 3);
      int vcb = ((l & 7) * 16) ^ ((vrow & 7) << 4);
      gload16(Vh + (size_t)vrow * 2048 + kv0 + (vcb >> 1), &Vs[w * 2048 + i * 512]);
    }
    __syncthreads();

    // S = Q @ K^T  (16 q-rows x 64 kv)
    f32x4 s[4] = {};
#pragma unroll
    for (int kk = 0; kk < 4; kk++) {
#pragma unroll
      for (int nb = 0; nb < 4; nb++) {
        int row = nb * 16 + lr;
        const char* p = (const char*)Ks + row * 256 + (((kk * 32 + lg * 8) * 2) ^ ((row & 7) << 4));
        bf16x8 kf = *(const bf16x8*)p;
        s[nb] = __builtin_amdgcn_mfma_f32_16x16x32_bf16(qf[kk], kf, s[nb], 0, 0, 0);
      }
    }

    // online softmax
    float pvv[4][4], corr[4];
    const bool diag = (kv0 == q0);
#pragma unroll
    for (int j = 0; j < 4; j++) {
      int qg = q0 + w * 16 + lg * 4 + j;
      float mx = -1e30f;
#pragma unroll
      for (int nb = 0; nb < 4; nb++) {
        float v = s[nb][j] * scale;
        if (diag) {
          int kg = kv0 + nb * 16 + lr;
          if (kg > qg) v = -1e30f;
        }
        s[nb][j] = v;
        mx = fmaxf(mx, v);
      }
      mx = fmaxf(mx, __shfl_xor(mx, 1));
      mx = fmaxf(mx, __shfl_xor(mx, 2));
      mx = fmaxf(mx, __shfl_xor(mx, 4));
      mx = fmaxf(mx, __shfl_xor(mx, 8));
      float mnew = fmaxf(mrun[j], mx);
      float c = __expf(mrun[j] - mnew);
      float ls = 0.f;
#pragma unroll
      for (int nb = 0; nb < 4; nb++) {
        float pe = __expf(s[nb][j] - mnew);
        pvv[nb][j] = pe; ls += pe;
      }
      ls += __shfl_xor(ls, 1);
      ls += __shfl_xor(ls, 2);
      ls += __shfl_xor(ls, 4);
      ls += __shfl_xor(ls, 8);
      mrun[j] = mnew;
      lrun[j] = lrun[j] * c + ls;
      corr[j] = c;
    }
#pragma unroll
    for (int df = 0; df < 8; df++)
#pragma unroll
      for (int j = 0; j < 4; j++) o[df][j] *= corr[j];

    // P -> LDS (C-layout -> A-layout fix via LDS roundtrip)
    char* Pw = (char*)&Ps[w][0];
#pragma unroll
    for (int nb = 0; nb < 4; nb++)
#pragma unroll
      for (int j = 0; j < 4; j++) {
        int qrow = lg * 4 + j;
        int kcol = nb * 16 + lr;
        *(bf16*)(Pw + qrow * 128 + ((kcol * 2) ^ ((qrow & 7) << 4))) = (bf16)pvv[nb][j];
      }
    __syncthreads();

    // O += P @ V
#pragma unroll
    for (int kk = 0; kk < 2; kk++) {
      bf16x8 pa = *(const bf16x8*)(Pw + lr * 128 + (((kk * 32 + lg * 8) * 2) ^ ((lr & 7) << 4)));
#pragma unroll
      for (int df = 0; df < 8; df++) {
        int vrow = df * 16 + lr;
        const char* vp = (const char*)Vs + vrow * 128 + (((kk * 32 + lg * 8) * 2) ^ ((vrow & 7) << 4));
        bf16x8 vb = *(const bf16x8*)vp;
        o[df] = __builtin_amdgcn_mfma_f32_16x16x32_bf16(pa, vb, o[df], 0, 0, 0);
      }
    }
  }

  // epilogue: O / l -> AO[b*T + q][h*128 + d]
#pragma unroll
  for (int j = 0; j < 4; j++) {
    int qg = q0 + w * 16 + lg * 4 + j;
    float inv = 1.f / lrun[j];
    bf16* op = AO + ((size_t)b * 2048 + qg) * 2048 + h * 128 + lr;
#pragma unroll
    for (int df = 0; df < 8; df++) op[df * 16] = (bf16)(o[df][j] * inv);
  }
}

// ---------------- launch ----------------
extern "C" void kernel_launch(void* const* d_in, const int* in_sizes, int n_in,
                              void* d_out, int out_size, void* d_ws, size_t ws_size,
                              hipStream_t stream) {
  const float* x  = (const float*)d_in[0];
  // d_in[1] = additive causal mask: implemented analytically, not read
  const float* wq = (const float*)d_in[2];
  const float* wk = (const float*)d_in[3];
  const float* wv = (const float*)d_in[4];
  const float* wo = (const float*)d_in[5];

  char* p = (char*)d_ws;
  auto alloc = [&](size_t bytes) { char* r = p; p += (bytes + 255) & ~(size_t)255; return r; };
  bf16*  xb   = (bf16*)alloc(8192ull * 2048 * 2);
  bf16*  wqT  = (bf16*)alloc(2048ull * 2048 * 2);
  bf16*  wkT  = (bf16*)alloc(512ull  * 2048 * 2);
  bf16*  wvT  = (bf16*)alloc(512ull  * 2048 * 2);
  bf16*  woT  = (bf16*)alloc(2048ull * 2048 * 2);
  f32x2* tab  = (f32x2*)alloc(2048ull * 64 * 8);
  bf16*  Qtmp = (bf16*)alloc(8192ull * 2048 * 2);   // later reused as attention output AO
  bf16*  Ktmp = (bf16*)alloc(8192ull * 512 * 2);
  bf16*  Qr   = (bf16*)alloc(8192ull * 2048 * 2);
  bf16*  Kr   = (bf16*)alloc(8192ull * 512 * 2);
  bf16*  Vr   = (bf16*)alloc(8192ull * 512 * 2);

  k_cvt<<<16384, 256, 0, stream>>>(x, xb);
  k_transpose_cvt<<<dim3(32, 32), 256, 0, stream>>>(wq, wqT, 2048, 2048);
  k_transpose_cvt<<<dim3(8, 32),  256, 0, stream>>>(wk, wkT, 2048, 512);
  k_transpose_cvt<<<dim3(8, 32),  256, 0, stream>>>(wv, wvT, 2048, 512);
  k_transpose_cvt<<<dim3(32, 32), 256, 0, stream>>>(wo, woT, 2048, 2048);
  k_rope_tab<<<512, 256, 0, stream>>>(tab);

  k_gemm<1><<<dim3(16, 64), 256, 0, stream>>>(xb, wqT, Qtmp, 8192, 2048, 2048);
  k_gemm<1><<<dim3(4, 64),  256, 0, stream>>>(xb, wkT, Ktmp, 8192, 512, 2048);
  k_gemm<2><<<dim3(4, 64),  256, 0, stream>>>(xb, wvT, Vr,   8192, 512, 2048);

  k_rope<4><<<8192, 256, 0, stream>>>(Qtmp, Qr, tab);  // Q: 16 heads
  k_rope<2><<<2048, 256, 0, stream>>>(Ktmp, Kr, tab);  // K: 4 kv heads

  k_attn<<<dim3(32, 64), 256, 0, stream>>>(Qr, Kr, Vr, Qtmp);

  k_gemm<0><<<dim3(16, 64), 256, 0, stream>>>(Qtmp, woT, d_out, 8192, 2048, 2048);
}

// Round 2
// 541.045 us; speedup vs baseline: 1.2008x; 1.2008x over previous
//
#include <hip/hip_runtime.h>

typedef __bf16 bf16;
typedef float  f32x4  __attribute__((ext_vector_type(4)));
typedef float  f32x2  __attribute__((ext_vector_type(2)));
typedef __bf16 bf16x8 __attribute__((ext_vector_type(8)));
typedef __bf16 bf16x4 __attribute__((ext_vector_type(4)));
typedef unsigned short ushort4_ __attribute__((ext_vector_type(4)));

typedef unsigned int __attribute__((address_space(1))) uint_g;
typedef unsigned int __attribute__((address_space(3))) uint_l;

#define DEV __device__ __forceinline__

DEV void gload16(const void* g, void* l) {
  // async global->LDS, 16B per lane; LDS dst is wave-uniform base + lane*16
  __builtin_amdgcn_global_load_lds((uint_g*)g, (uint_l*)l, 16, 0, 0);
}

// ---------------- fp32 -> bf16 convert (vectorized) ----------------
__global__ void k_cvt(const float* __restrict__ in, bf16* __restrict__ out) {
  int i = blockIdx.x * 256 + threadIdx.x;          // one float4 per thread
  f32x4 v = *((const f32x4*)in + i);
  bf16x4 o;
  o[0] = (bf16)v[0]; o[1] = (bf16)v[1]; o[2] = (bf16)v[2]; o[3] = (bf16)v[3];
  *((bf16x4*)out + i) = o;
}

// ---------------- [K][N] fp32 -> [N][K] bf16 transpose ----------------
__global__ void k_transpose_cvt(const float* __restrict__ in, bf16* __restrict__ out,
                                int K, int N) {
  __shared__ bf16 tile[64][65];
  int n0 = blockIdx.x * 64, k0 = blockIdx.y * 64;
  int tx = threadIdx.x & 63, ty = threadIdx.x >> 6;
#pragma unroll
  for (int r = 0; r < 64; r += 4)
    tile[r + ty][tx] = (bf16)in[(size_t)(k0 + r + ty) * N + n0 + tx];
  __syncthreads();
#pragma unroll
  for (int r = 0; r < 64; r += 4)
    out[(size_t)(n0 + r + ty) * K + k0 + tx] = tile[tx][r + ty];
}

// ---------------- RoPE cos/sin table: [T][64] of (cos,sin) ----------------
__global__ void k_rope_tab(f32x2* __restrict__ tab) {
  int idx = blockIdx.x * 256 + threadIdx.x;   // T*64
  int t = idx >> 6, i = idx & 63;
  float inv = powf(10000.f, -(float)i * (1.f / 64.f));
  float ang = (float)t * inv;
  f32x2 cs; cs[0] = cosf(ang); cs[1] = sinf(ang);
  tab[idx] = cs;
}

// ---------------- m97-style GEMM: C = A @ Bt^T ----------------
// A [M][K] bf16 row-major, Bt [N][K] bf16 row-major.
// MODE 0: C fp32 [M][N]. MODE 1: C bf16 [M][N].
// MODE 2: C bf16 V-transpose: out[b][kv][d][t] with row=b*2048+t, col=kv*128+d.
template <int MODE>
__global__ __launch_bounds__(256) void k_gemm(const bf16* __restrict__ A,
                                              const bf16* __restrict__ Bt,
                                              void* __restrict__ C,
                                              int M, int N, int K) {
  __shared__ bf16 As[128 * 32];
  __shared__ bf16 Bs[128 * 32];
  const int tid = threadIdx.x;
  const int w = tid >> 6, l = tid & 63;
  const int bm = blockIdx.y, bn = blockIdx.x;
  const int wr = w >> 1, wc = w & 1;
  const int lr = l & 15, lg = l >> 4;

  const bf16* ag = A  + (size_t)(bm * 128 + w * 16 + (l >> 2)) * K + (l & 3) * 8;
  const bf16* bg = Bt + (size_t)(bn * 128 + w * 16 + (l >> 2)) * K + (l & 3) * 8;
  bf16* as0 = &As[w * 512];
  bf16* as1 = &As[64 * 32 + w * 512];
  bf16* bs0 = &Bs[w * 512];
  bf16* bs1 = &Bs[64 * 32 + w * 512];
  const size_t astep = (size_t)64 * K;

  f32x4 acc[4][4] = {};

  for (int k0 = 0; k0 < K; k0 += 32) {
    __syncthreads();
    gload16(ag, as0);
    gload16(ag + astep, as1);
    gload16(bg, bs0);
    gload16(bg + astep, bs1);
    ag += 32; bg += 32;
    __syncthreads();
    bf16x8 af[4], bfr[4];
#pragma unroll
    for (int m = 0; m < 4; m++)
      af[m] = *(const bf16x8*)&As[(wr * 64 + m * 16 + lr) * 32 + lg * 8];
#pragma unroll
    for (int n = 0; n < 4; n++)
      bfr[n] = *(const bf16x8*)&Bs[(wc * 64 + n * 16 + lr) * 32 + lg * 8];
#pragma unroll
    for (int m = 0; m < 4; m++)
#pragma unroll
      for (int n = 0; n < 4; n++)
        acc[m][n] = __builtin_amdgcn_mfma_f32_16x16x32_bf16(af[m], bfr[n], acc[m][n], 0, 0, 0);
  }

  const int row0 = bm * 128 + wr * 64;
  const int col0 = bn * 128 + wc * 64;
#pragma unroll
  for (int m = 0; m < 4; m++) {
#pragma unroll
    for (int n = 0; n < 4; n++) {
      int col = col0 + n * 16 + lr;
      if constexpr (MODE == 0) {
        float* Cf = (float*)C;
#pragma unroll
        for (int j = 0; j < 4; j++) {
          int row = row0 + m * 16 + lg * 4 + j;
          Cf[(size_t)row * N + col] = acc[m][n][j];
        }
      } else if constexpr (MODE == 1) {
        bf16* Cb = (bf16*)C;
#pragma unroll
        for (int j = 0; j < 4; j++) {
          int row = row0 + m * 16 + lg * 4 + j;
          Cb[(size_t)row * N + col] = (bf16)acc[m][n][j];
        }
      } else {
        bf16* Cb = (bf16*)C;
        int rowb = row0 + m * 16 + lg * 4;        // 4 consecutive tokens
        int bb = rowb >> 11, t0 = rowb & 2047;
        size_t off = ((size_t)((bb * 4 + (col >> 7)) * 128 + (col & 127))) * 2048 + t0;
        ushort4_ pk;
#pragma unroll
        for (int j = 0; j < 4; j++)
          pk[j] = __builtin_bit_cast(unsigned short, (bf16)acc[m][n][j]);
        *(ushort4_*)(Cb + off) = pk;
      }
    }
  }
}

// ---------------- RoPE + rearrange: [B*T][NH*128] -> [B][NH][T][128] ----------------
template <int LOGNH>
__global__ void k_rope(const bf16* __restrict__ in, bf16* __restrict__ out,
                       const f32x2* __restrict__ tab) {
  const int NH = 1 << LOGNH;
  int idx = blockIdx.x * 256 + threadIdx.x;
  int dq = idx & 15;                        // d0 = dq*4
  int h = (idx >> 4) & (NH - 1);
  int bt = idx >> (4 + LOGNH);
  int t = bt & 2047;
  int d0 = dq * 4;
  const bf16* pin = in + (size_t)bt * (NH * 128) + h * 128;
  bf16x4 x1 = *(const bf16x4*)(pin + d0);
  bf16x4 x2 = *(const bf16x4*)(pin + 64 + d0);
  bf16x4 o1, o2;
#pragma unroll
  for (int j = 0; j < 4; j++) {
    f32x2 cs = tab[t * 64 + d0 + j];
    float a = (float)x1[j], c2 = (float)x2[j];
    o1[j] = (bf16)(a * cs[0] - c2 * cs[1]);
    o2[j] = (bf16)(c2 * cs[0] + a * cs[1]);
  }
  int b = bt >> 11;
  bf16* pout = out + (((size_t)(b << LOGNH) + h) * 2048 + t) * 128;
  *(bf16x4*)(pout + d0) = o1;
  *(bf16x4*)(pout + 64 + d0) = o2;
}

// ---------------- flash attention (causal, GQA), swapped-operand form ----------------
// Qb [B][16][T][128], Kb [B][4][T][128] (rope'd), Vt [B][4][128][T], AO [B*T][2048]
// Block: 4 waves x 32 q-rows = 128 q-rows. Per wave:
//   S^T[kv64][q32] = mfma(K_frag(A), Q_frag(B))  -> lane owns q = lane&15, 16 kv/reg-set
//   softmax per lane: in-reg fmax/sum + 2 shfls (xor16/32)
//   P^T -> per-wave LDS tile (8B swizzled writes), read back as B-frag (16B)
//   O^T[d128][q32] += mfma(Vt_frag(A), P_frag(B)) -> col = q = lane&15 (rescale lane-local)
__global__ __launch_bounds__(256, 2) void k_attn(const bf16* __restrict__ Qb,
                                                 const bf16* __restrict__ Kb,
                                                 const bf16* __restrict__ Vt,
                                                 bf16* __restrict__ AO) {
  __shared__ bf16 Ks[64 * 128];    // [kv 64][d 128], XOR-swizzled rows
  __shared__ bf16 Vs[128 * 64];    // [d 128][kv 64], XOR-swizzled rows
  __shared__ bf16 Ps[4][32 * 64];  // per-wave P[qloc 32][kv 64], swizzled
  const int tid = threadIdx.x, w = tid >> 6, l = tid & 63;
  const int bh = blockIdx.y, b = bh >> 4, h = bh & 15, kvh = h >> 2;
  const int q0 = (15 - blockIdx.x) * 128;       // heavy blocks dispatched first
  const int lr = l & 15, lg = l >> 4;
  const float scale = 0.08838834764831845f;

  // Q fragments (resident): qf[nq][kk] = Q[q0 + w*32 + nq*16 + lr][kk*32 + lg*8 ..]
  bf16x8 qf[2][4];
#pragma unroll
  for (int nq = 0; nq < 2; nq++) {
    const bf16* qp = Qb + (((size_t)(b * 16 + h) * 2048) + q0 + w * 32 + nq * 16 + lr) * 128 + lg * 8;
#pragma unroll
    for (int kk = 0; kk < 4; kk++) qf[nq][kk] = *(const bf16x8*)(qp + kk * 32);
  }
  const bf16* Kh = Kb + (size_t)(b * 4 + kvh) * (2048 * 128);
  const bf16* Vh = Vt + (size_t)(b * 4 + kvh) * (128 * 2048);

  f32x4 ot[8][2] = {};            // O^T: row d = df*16 + lg*4 + j, col q = nq*16 + lr
  float mrun[2] = {-1e30f, -1e30f}, lrun[2] = {0.f, 0.f};
  const int qmaxw = q0 + w * 32 + 31;
  char* Pw = (char*)&Ps[w][0];

  for (int kv0 = 0; kv0 <= q0 + 64; kv0 += 64) {
    __syncthreads();
    // stage K[kv0+0:64][0:128] and Vt[0:128][kv0+0:64], source pre-swizzled (rule #21)
#pragma unroll
    for (int i = 0; i < 4; i++) {
      int krow = w * 16 + i * 4 + lg;
      int kcb = ((l & 15) * 16) ^ ((krow & 7) << 4);
      gload16(Kh + (size_t)(kv0 + krow) * 128 + (kcb >> 1), &Ks[w * 2048 + i * 512]);
      int vrow = w * 32 + i * 8 + (l >> 3);
      int vcb = ((l & 7) * 16) ^ ((vrow & 7) << 4);
      gload16(Vh + (size_t)vrow * 2048 + kv0 + (vcb >> 1), &Vs[w * 2048 + i * 512]);
    }
    __syncthreads();
    if (kv0 > qmaxw) continue;    // fully-masked for this wave (barrier counts stay uniform)

    // S^T = K @ Q^T : st[nb][nq], rows kv = nb*16 + lg*4 + j, col q = nq*16 + lr
    f32x4 st[4][2] = {};
#pragma unroll
    for (int kk = 0; kk < 4; kk++) {
#pragma unroll
      for (int nb = 0; nb < 4; nb++) {
        int row = nb * 16 + lr;
        const char* p = (const char*)Ks + row * 256 + ((kk * 64 + lg * 16) ^ ((lr & 7) << 4));
        bf16x8 kf = *(const bf16x8*)p;
#pragma unroll
        for (int nq = 0; nq < 2; nq++)
          st[nb][nq] = __builtin_amdgcn_mfma_f32_16x16x32_bf16(kf, qf[nq][kk], st[nb][nq], 0, 0, 0);
      }
    }

    // online softmax: per lane, q = nq*16 + lr; kv values in-register
    const bool needmask = (kv0 + 63 > q0 + w * 32);
    float corr_[2];
#pragma unroll
    for (int nq = 0; nq < 2; nq++) {
      const int qg = q0 + w * 32 + nq * 16 + lr;
      float pv[4][4];
      float mx = -1e30f;
#pragma unroll
      for (int nb = 0; nb < 4; nb++)
#pragma unroll
        for (int j = 0; j < 4; j++) {
          float v = st[nb][nq][j] * scale;
          if (needmask) {
            int kg = kv0 + nb * 16 + lg * 4 + j;
            if (kg > qg) v = -1e30f;
          }
          pv[nb][j] = v;
          mx = fmaxf(mx, v);
        }
      mx = fmaxf(mx, __shfl_xor(mx, 16));
      mx = fmaxf(mx, __shfl_xor(mx, 32));
      float mnew = fmaxf(mrun[nq], mx);
      float c = __expf(mrun[nq] - mnew);
      float ls = 0.f;
#pragma unroll
      for (int nb = 0; nb < 4; nb++)
#pragma unroll
        for (int j = 0; j < 4; j++) {
          float pe = __expf(pv[nb][j] - mnew);
          pv[nb][j] = pe;
          ls += pe;
        }
      ls += __shfl_xor(ls, 16);
      ls += __shfl_xor(ls, 32);
      mrun[nq] = mnew;
      lrun[nq] = lrun[nq] * c + ls;
      corr_[nq] = c;

      // P^T -> per-wave LDS as P[qloc][kv], vectorized 8B swizzled writes
      const int qloc = nq * 16 + lr;
#pragma unroll
      for (int nb = 0; nb < 4; nb++) {
        ushort4_ pk;
#pragma unroll
        for (int j = 0; j < 4; j++)
          pk[j] = __builtin_bit_cast(unsigned short, (bf16)pv[nb][j]);
        *(ushort4_*)(Pw + qloc * 128 + ((nb * 32 + lg * 8) ^ ((qloc & 7) << 4))) = pk;
      }
    }
#pragma unroll
    for (int df = 0; df < 8; df++)
#pragma unroll
      for (int nq = 0; nq < 2; nq++)
        ot[df][nq] *= corr_[nq];

    // O^T += V^T @ P^T  (A = V^T rows d, B = P cols q)
#pragma unroll
    for (int s = 0; s < 2; s++) {
      bf16x8 pf[2];
#pragma unroll
      for (int nq = 0; nq < 2; nq++) {
        int qloc = nq * 16 + lr;
        pf[nq] = *(const bf16x8*)(Pw + qloc * 128 + ((s * 64 + lg * 16) ^ ((qloc & 7) << 4)));
      }
#pragma unroll
      for (int df = 0; df < 8; df++) {
        int vrow = df * 16 + lr;
        const char* vp = (const char*)Vs + vrow * 128 + ((s * 64 + lg * 16) ^ ((lr & 7) << 4));
        bf16x8 vf = *(const bf16x8*)vp;
#pragma unroll
        for (int nq = 0; nq < 2; nq++)
          ot[df][nq] = __builtin_amdgcn_mfma_f32_16x16x32_bf16(vf, pf[nq], ot[df][nq], 0, 0, 0);
      }
    }
  }

  // epilogue: O^T / l -> AO[b*T + q][h*128 + d]; all factors lane-local
#pragma unroll
  for (int nq = 0; nq < 2; nq++) {
    float inv = 1.f / lrun[nq];
    int qg = q0 + w * 32 + nq * 16 + lr;
    bf16* op = AO + ((size_t)b * 2048 + qg) * 2048 + h * 128;
#pragma unroll
    for (int df = 0; df < 8; df++) {
      ushort4_ pk;
#pragma unroll
      for (int j = 0; j < 4; j++)
        pk[j] = __builtin_bit_cast(unsigned short, (bf16)(ot[df][nq][j] * inv));
      *(ushort4_*)(op + df * 16 + lg * 4) = pk;
    }
  }
}

// ---------------- launch ----------------
extern "C" void kernel_launch(void* const* d_in, const int* in_sizes, int n_in,
                              void* d_out, int out_size, void* d_ws, size_t ws_size,
                              hipStream_t stream) {
  const float* x  = (const float*)d_in[0];
  // d_in[1] = additive causal mask: implemented analytically, not read
  const float* wq = (const float*)d_in[2];
  const float* wk = (const float*)d_in[3];
  const float* wv = (const float*)d_in[4];
  const float* wo = (const float*)d_in[5];

  char* p = (char*)d_ws;
  auto alloc = [&](size_t bytes) { char* r = p; p += (bytes + 255) & ~(size_t)255; return r; };
  bf16*  xb   = (bf16*)alloc(8192ull * 2048 * 2);
  bf16*  wqT  = (bf16*)alloc(2048ull * 2048 * 2);
  bf16*  wkT  = (bf16*)alloc(512ull  * 2048 * 2);
  bf16*  wvT  = (bf16*)alloc(512ull  * 2048 * 2);
  bf16*  woT  = (bf16*)alloc(2048ull * 2048 * 2);
  f32x2* tab  = (f32x2*)alloc(2048ull * 64 * 8);
  bf16*  Qtmp = (bf16*)alloc(8192ull * 2048 * 2);   // later reused as attention output AO
  bf16*  Ktmp = (bf16*)alloc(8192ull * 512 * 2);
  bf16*  Qr   = (bf16*)alloc(8192ull * 2048 * 2);
  bf16*  Kr   = (bf16*)alloc(8192ull * 512 * 2);
  bf16*  Vr   = (bf16*)alloc(8192ull * 512 * 2);

  k_cvt<<<16384, 256, 0, stream>>>(x, xb);
  k_transpose_cvt<<<dim3(32, 32), 256, 0, stream>>>(wq, wqT, 2048, 2048);
  k_transpose_cvt<<<dim3(8, 32),  256, 0, stream>>>(wk, wkT, 2048, 512);
  k_transpose_cvt<<<dim3(8, 32),  256, 0, stream>>>(wv, wvT, 2048, 512);
  k_transpose_cvt<<<dim3(32, 32), 256, 0, stream>>>(wo, woT, 2048, 2048);
  k_rope_tab<<<512, 256, 0, stream>>>(tab);

  k_gemm<1><<<dim3(16, 64), 256, 0, stream>>>(xb, wqT, Qtmp, 8192, 2048, 2048);
  k_gemm<1><<<dim3(4, 64),  256, 0, stream>>>(xb, wkT, Ktmp, 8192, 512, 2048);
  k_gemm<2><<<dim3(4, 64),  256, 0, stream>>>(xb, wvT, Vr,   8192, 512, 2048);

  k_rope<4><<<8192, 256, 0, stream>>>(Qtmp, Qr, tab);  // Q: 16 heads
  k_rope<2><<<2048, 256, 0, stream>>>(Ktmp, Kr, tab);  // K: 4 kv heads

  k_attn<<<dim3(16, 64), 256, 0, stream>>>(Qr, Kr, Vr, Qtmp);

  k_gemm<0><<<dim3(16, 64), 256, 0, stream>>>(Qtmp, woT, d_out, 8192, 2048, 2048);
}

// Round 3
// 480.345 us; speedup vs baseline: 1.3525x; 1.1264x over previous
//
#include <hip/hip_runtime.h>

typedef __bf16 bf16;
typedef float  f32x4  __attribute__((ext_vector_type(4)));
typedef float  f32x2  __attribute__((ext_vector_type(2)));
typedef __bf16 bf16x8 __attribute__((ext_vector_type(8)));
typedef __bf16 bf16x4 __attribute__((ext_vector_type(4)));
typedef unsigned short ushort4_ __attribute__((ext_vector_type(4)));

typedef unsigned int __attribute__((address_space(1))) uint_g;
typedef unsigned int __attribute__((address_space(3))) uint_l;

#define DEV __device__ __forceinline__

DEV void gload16(const void* g, void* l) {
  // async global->LDS, 16B per lane; LDS dst is wave-uniform base + lane*16
  __builtin_amdgcn_global_load_lds((uint_g*)g, (uint_l*)l, 16, 0, 0);
}

// ---------------- fp32 -> bf16 convert (vectorized) ----------------
__global__ void k_cvt(const float* __restrict__ in, bf16* __restrict__ out) {
  int i = blockIdx.x * 256 + threadIdx.x;          // one float4 per thread
  f32x4 v = *((const f32x4*)in + i);
  bf16x4 o;
  o[0] = (bf16)v[0]; o[1] = (bf16)v[1]; o[2] = (bf16)v[2]; o[3] = (bf16)v[3];
  *((bf16x4*)out + i) = o;
}

// ---------------- [K][N] fp32 -> [N][K] bf16 transpose ----------------
__global__ void k_transpose_cvt(const float* __restrict__ in, bf16* __restrict__ out,
                                int K, int N) {
  __shared__ bf16 tile[64][65];
  int n0 = blockIdx.x * 64, k0 = blockIdx.y * 64;
  int tx = threadIdx.x & 63, ty = threadIdx.x >> 6;
#pragma unroll
  for (int r = 0; r < 64; r += 4)
    tile[r + ty][tx] = (bf16)in[(size_t)(k0 + r + ty) * N + n0 + tx];
  __syncthreads();
#pragma unroll
  for (int r = 0; r < 64; r += 4)
    out[(size_t)(n0 + r + ty) * K + k0 + tx] = tile[tx][r + ty];
}

// ---------------- RoPE cos/sin table: [T][64] of (cos,sin) ----------------
__global__ void k_rope_tab(f32x2* __restrict__ tab) {
  int idx = blockIdx.x * 256 + threadIdx.x;   // T*64
  int t = idx >> 6, i = idx & 63;
  float inv = powf(10000.f, -(float)i * (1.f / 64.f));
  float ang = (float)t * inv;
  f32x2 cs; cs[0] = cosf(ang); cs[1] = sinf(ang);
  tab[idx] = cs;
}

// ---------------- m97-style GEMM: C = A @ Bt^T ----------------
// A [M][K] bf16 row-major, Bt [N][K] bf16 row-major.
// MODE 0: C fp32 [M][N]. MODE 1: C bf16 [M][N].
// MODE 2: C bf16 V-transpose: out[b][kv][d][t] with row=b*2048+t, col=kv*128+d.
template <int MODE>
__global__ __launch_bounds__(256) void k_gemm(const bf16* __restrict__ A,
                                              const bf16* __restrict__ Bt,
                                              void* __restrict__ C,
                                              int M, int N, int K) {
  __shared__ bf16 As[128 * 32];
  __shared__ bf16 Bs[128 * 32];
  const int tid = threadIdx.x;
  const int w = tid >> 6, l = tid & 63;
  const int bm = blockIdx.y, bn = blockIdx.x;
  const int wr = w >> 1, wc = w & 1;
  const int lr = l & 15, lg = l >> 4;

  const bf16* ag = A  + (size_t)(bm * 128 + w * 16 + (l >> 2)) * K + (l & 3) * 8;
  const bf16* bg = Bt + (size_t)(bn * 128 + w * 16 + (l >> 2)) * K + (l & 3) * 8;
  bf16* as0 = &As[w * 512];
  bf16* as1 = &As[64 * 32 + w * 512];
  bf16* bs0 = &Bs[w * 512];
  bf16* bs1 = &Bs[64 * 32 + w * 512];
  const size_t astep = (size_t)64 * K;

  f32x4 acc[4][4] = {};

  for (int k0 = 0; k0 < K; k0 += 32) {
    __syncthreads();
    gload16(ag, as0);
    gload16(ag + astep, as1);
    gload16(bg, bs0);
    gload16(bg + astep, bs1);
    ag += 32; bg += 32;
    __syncthreads();
    bf16x8 af[4], bfr[4];
#pragma unroll
    for (int m = 0; m < 4; m++)
      af[m] = *(const bf16x8*)&As[(wr * 64 + m * 16 + lr) * 32 + lg * 8];
#pragma unroll
    for (int n = 0; n < 4; n++)
      bfr[n] = *(const bf16x8*)&Bs[(wc * 64 + n * 16 + lr) * 32 + lg * 8];
#pragma unroll
    for (int m = 0; m < 4; m++)
#pragma unroll
      for (int n = 0; n < 4; n++)
        acc[m][n] = __builtin_amdgcn_mfma_f32_16x16x32_bf16(af[m], bfr[n], acc[m][n], 0, 0, 0);
  }

  const int row0 = bm * 128 + wr * 64;
  const int col0 = bn * 128 + wc * 64;
#pragma unroll
  for (int m = 0; m < 4; m++) {
#pragma unroll
    for (int n = 0; n < 4; n++) {
      int col = col0 + n * 16 + lr;
      if constexpr (MODE == 0) {
        float* Cf = (float*)C;
#pragma unroll
        for (int j = 0; j < 4; j++) {
          int row = row0 + m * 16 + lg * 4 + j;
          Cf[(size_t)row * N + col] = acc[m][n][j];
        }
      } else if constexpr (MODE == 1) {
        bf16* Cb = (bf16*)C;
#pragma unroll
        for (int j = 0; j < 4; j++) {
          int row = row0 + m * 16 + lg * 4 + j;
          Cb[(size_t)row * N + col] = (bf16)acc[m][n][j];
        }
      } else {
        bf16* Cb = (bf16*)C;
        int rowb = row0 + m * 16 + lg * 4;        // 4 consecutive tokens
        int bb = rowb >> 11, t0 = rowb & 2047;
        size_t off = ((size_t)((bb * 4 + (col >> 7)) * 128 + (col & 127))) * 2048 + t0;
        ushort4_ pk;
#pragma unroll
        for (int j = 0; j < 4; j++)
          pk[j] = __builtin_bit_cast(unsigned short, (bf16)acc[m][n][j]);
        *(ushort4_*)(Cb + off) = pk;
      }
    }
  }
}

// ---------------- RoPE + rearrange: [B*T][NH*128] -> [B][NH][T][128] ----------------
template <int LOGNH>
__global__ void k_rope(const bf16* __restrict__ in, bf16* __restrict__ out,
                       const f32x2* __restrict__ tab) {
  const int NH = 1 << LOGNH;
  int idx = blockIdx.x * 256 + threadIdx.x;
  int dq = idx & 15;                        // d0 = dq*4
  int h = (idx >> 4) & (NH - 1);
  int bt = idx >> (4 + LOGNH);
  int t = bt & 2047;
  int d0 = dq * 4;
  const bf16* pin = in + (size_t)bt * (NH * 128) + h * 128;
  bf16x4 x1 = *(const bf16x4*)(pin + d0);
  bf16x4 x2 = *(const bf16x4*)(pin + 64 + d0);
  bf16x4 o1, o2;
#pragma unroll
  for (int j = 0; j < 4; j++) {
    f32x2 cs = tab[t * 64 + d0 + j];
    float a = (float)x1[j], c2 = (float)x2[j];
    o1[j] = (bf16)(a * cs[0] - c2 * cs[1]);
    o2[j] = (bf16)(c2 * cs[0] + a * cs[1]);
  }
  int b = bt >> 11;
  bf16* pout = out + (((size_t)(b << LOGNH) + h) * 2048 + t) * 128;
  *(bf16x4*)(pout + d0) = o1;
  *(bf16x4*)(pout + 64 + d0) = o2;
}

// ---------------- flash attention (causal, GQA), swapped-operand + pipelined ----------------
// Qb [B][16][T][128], Kb [B][4][T][128] (rope'd), Vt [B][4][128][T], AO [B*T][2048]
// Block handles the q-block PAIR (pi, 15-pi): uniform 36 tiles/block, grid 8x64 = 512 = 2/CU.
// Per tile: issue V(t)+K(t+1) async stages, compute QK^T+softmax (loads fly under it),
// barrier (drains stages), PV, barrier. K double-buffered; V single (consumed same tile).
__global__ __launch_bounds__(256, 2) void k_attn(const bf16* __restrict__ Qb,
                                                 const bf16* __restrict__ Kb,
                                                 const bf16* __restrict__ Vt,
                                                 bf16* __restrict__ AO) {
  __shared__ bf16 Ks[2][64 * 128];  // 32KB, [kv 64][d 128] XOR-swizzled rows
  __shared__ bf16 Vs[128 * 64];     // 16KB, [d 128][kv 64] XOR-swizzled rows
  __shared__ bf16 Ps[4][32 * 64];   // 16KB, per-wave P[qloc 32][kv 64], swizzled
  const int tid = threadIdx.x, w = tid >> 6, l = tid & 63;
  const int bh = blockIdx.y, b = bh >> 4, h = bh & 15, kvh = h >> 2;
  const int pi = blockIdx.x;
  const int lr = l & 15, lg = l >> 4;
  const float cc = 0.08838834764831845f * 1.4426950408889634f;  // scale * log2(e)

  const bf16* Kh = Kb + (size_t)(b * 4 + kvh) * (2048 * 128);
  const bf16* Vh = Vt + (size_t)(b * 4 + kvh) * (128 * 2048);
  char* Pw = (char*)&Ps[w][0];

  auto stageV = [&](int kv0) {
#pragma unroll
    for (int i = 0; i < 4; i++) {
      int vrow = w * 32 + i * 8 + (l >> 3);
      int vcb = ((l & 7) * 16) ^ ((vrow & 7) << 4);
      gload16(Vh + (size_t)vrow * 2048 + kv0 + (vcb >> 1), (bf16*)Vs + w * 2048 + i * 512);
    }
  };
  auto stageK = [&](int kv0, int buf) {
#pragma unroll
    for (int i = 0; i < 4; i++) {
      int krow = w * 16 + i * 4 + lg;
      int kcb = ((l & 15) * 16) ^ ((krow & 7) << 4);
      gload16(Kh + (size_t)(kv0 + krow) * 128 + (kcb >> 1), &Ks[buf][w * 2048 + i * 512]);
    }
  };

#pragma unroll 1
  for (int ph = 0; ph < 2; ph++) {
    const int q0 = (ph ? (15 - pi) : pi) * 128;
    const int nt = q0 / 64 + 2;
    const int qmaxw = q0 + w * 32 + 31;

    bf16x8 qf[2][4];
#pragma unroll
    for (int nq = 0; nq < 2; nq++) {
      const bf16* qp = Qb + (((size_t)(b * 16 + h) * 2048) + q0 + w * 32 + nq * 16 + lr) * 128 + lg * 8;
#pragma unroll
      for (int kk = 0; kk < 4; kk++) qf[nq][kk] = *(const bf16x8*)(qp + kk * 32);
    }

    f32x4 ot[8][2] = {};
    float m_[2] = {-1e30f, -1e30f}, l_[2] = {0.f, 0.f};

    int cur = 0;
    stageK(0, 0);
    __syncthreads();

#pragma unroll 1
    for (int t = 0; t < nt; t++) {
      const int kv0 = t * 64;
      stageV(kv0);
      if (t + 1 < nt) stageK(kv0 + 64, cur ^ 1);
      const bool act = (kv0 <= qmaxw);

      if (act) {
        // S^T = K @ Q^T (raw units): st[nb][nq], rows kv = nb*16+lg*4+j, col q = nq*16+lr
        f32x4 st[4][2] = {};
        __builtin_amdgcn_s_setprio(1);
#pragma unroll
        for (int kk = 0; kk < 4; kk++) {
#pragma unroll
          for (int nb = 0; nb < 4; nb++) {
            int row = nb * 16 + lr;
            const char* p = (const char*)&Ks[cur][0] + row * 256 + ((kk * 64 + lg * 16) ^ ((lr & 7) << 4));
            bf16x8 kf = *(const bf16x8*)p;
#pragma unroll
            for (int nq = 0; nq < 2; nq++)
              st[nb][nq] = __builtin_amdgcn_mfma_f32_16x16x32_bf16(kf, qf[nq][kk], st[nb][nq], 0, 0, 0);
          }
        }
        __builtin_amdgcn_s_setprio(0);

        // mask + per-lane max (raw units)
        const bool needmask = (kv0 + 63 > q0 + w * 32);
        float pv[2][4][4], pmax[2];
#pragma unroll
        for (int nq = 0; nq < 2; nq++) {
          const int qg = q0 + w * 32 + nq * 16 + lr;
          float mx = -1e30f;
#pragma unroll
          for (int nb = 0; nb < 4; nb++)
#pragma unroll
            for (int j = 0; j < 4; j++) {
              float v = st[nb][nq][j];
              if (needmask) {
                int kg = kv0 + nb * 16 + lg * 4 + j;
                if (kg > qg) v = -1e30f;
              }
              pv[nq][nb][j] = v;
              mx = fmaxf(mx, v);
            }
          pmax[nq] = mx;
        }
        // defer-max: only rescale when some row grew past m + 64 (raw; *cc in exp2 domain)
        if (!__all(fmaxf(pmax[0] - m_[0], pmax[1] - m_[1]) <= 64.f)) {
          float corr[2];
#pragma unroll
          for (int nq = 0; nq < 2; nq++) {
            float mx = pmax[nq];
            mx = fmaxf(mx, __shfl_xor(mx, 16));
            mx = fmaxf(mx, __shfl_xor(mx, 32));
            float mnew = fmaxf(m_[nq], mx);
            corr[nq] = exp2f((m_[nq] - mnew) * cc);
            m_[nq] = mnew;
            l_[nq] *= corr[nq];
          }
#pragma unroll
          for (int df = 0; df < 8; df++)
#pragma unroll
            for (int nq = 0; nq < 2; nq++)
              ot[df][nq] *= corr[nq];
        }
        // P = exp2((s - m)*cc), row-sum, P -> per-wave LDS (8B swizzled stores)
#pragma unroll
        for (int nq = 0; nq < 2; nq++) {
          float ls = 0.f;
#pragma unroll
          for (int nb = 0; nb < 4; nb++)
#pragma unroll
            for (int j = 0; j < 4; j++) {
              float pe = exp2f((pv[nq][nb][j] - m_[nq]) * cc);
              pv[nq][nb][j] = pe;
              ls += pe;
            }
          ls += __shfl_xor(ls, 16);
          ls += __shfl_xor(ls, 32);
          l_[nq] += ls;
          const int qloc = nq * 16 + lr;
#pragma unroll
          for (int nb = 0; nb < 4; nb++) {
            ushort4_ pk;
#pragma unroll
            for (int j = 0; j < 4; j++)
              pk[j] = __builtin_bit_cast(unsigned short, (bf16)pv[nq][nb][j]);
            *(ushort4_*)(Pw + qloc * 128 + ((nb * 32 + lg * 8) ^ ((qloc & 7) << 4))) = pk;
          }
        }
      }

      __syncthreads();   // drains vmcnt: V(t) + K(t+1) landed for ALL waves

      if (act) {
        // O^T += V^T @ P^T
        __builtin_amdgcn_s_setprio(1);
#pragma unroll
        for (int s = 0; s < 2; s++) {
          bf16x8 pf[2];
#pragma unroll
          for (int nq = 0; nq < 2; nq++) {
            int qloc = nq * 16 + lr;
            pf[nq] = *(const bf16x8*)(Pw + qloc * 128 + ((s * 64 + lg * 16) ^ ((qloc & 7) << 4)));
          }
#pragma unroll
          for (int df = 0; df < 8; df++) {
            int vrow = df * 16 + lr;
            const char* vp = (const char*)Vs + vrow * 128 + ((s * 64 + lg * 16) ^ ((lr & 7) << 4));
            bf16x8 vf = *(const bf16x8*)vp;
#pragma unroll
            for (int nq = 0; nq < 2; nq++)
              ot[df][nq] = __builtin_amdgcn_mfma_f32_16x16x32_bf16(vf, pf[nq], ot[df][nq], 0, 0, 0);
          }
        }
        __builtin_amdgcn_s_setprio(0);
      }

      __syncthreads();   // all waves done reading Vs / Ks[cur] before next-iter overwrite
      cur ^= 1;
    }

    // epilogue: O^T / l -> AO[b*T + q][h*128 + d]; factors lane-local
#pragma unroll
    for (int nq = 0; nq < 2; nq++) {
      float inv = 1.f / l_[nq];
      int qg = q0 + w * 32 + nq * 16 + lr;
      bf16* op = AO + ((size_t)b * 2048 + qg) * 2048 + h * 128;
#pragma unroll
      for (int df = 0; df < 8; df++) {
        ushort4_ pk;
#pragma unroll
        for (int j = 0; j < 4; j++)
          pk[j] = __builtin_bit_cast(unsigned short, (bf16)(ot[df][nq][j] * inv));
        *(ushort4_*)(op + df * 16 + lg * 4) = pk;
      }
    }
  }
}

// ---------------- launch ----------------
extern "C" void kernel_launch(void* const* d_in, const int* in_sizes, int n_in,
                              void* d_out, int out_size, void* d_ws, size_t ws_size,
                              hipStream_t stream) {
  const float* x  = (const float*)d_in[0];
  // d_in[1] = additive causal mask: implemented analytically, not read
  const float* wq = (const float*)d_in[2];
  const float* wk = (const float*)d_in[3];
  const float* wv = (const float*)d_in[4];
  const float* wo = (const float*)d_in[5];

  char* p = (char*)d_ws;
  auto alloc = [&](size_t bytes) { char* r = p; p += (bytes + 255) & ~(size_t)255; return r; };
  bf16*  xb   = (bf16*)alloc(8192ull * 2048 * 2);
  bf16*  wqT  = (bf16*)alloc(2048ull * 2048 * 2);
  bf16*  wkT  = (bf16*)alloc(512ull  * 2048 * 2);
  bf16*  wvT  = (bf16*)alloc(512ull  * 2048 * 2);
  bf16*  woT  = (bf16*)alloc(2048ull * 2048 * 2);
  f32x2* tab  = (f32x2*)alloc(2048ull * 64 * 8);
  bf16*  Qtmp = (bf16*)alloc(8192ull * 2048 * 2);   // later reused as attention output AO
  bf16*  Ktmp = (bf16*)alloc(8192ull * 512 * 2);
  bf16*  Qr   = (bf16*)alloc(8192ull * 2048 * 2);
  bf16*  Kr   = (bf16*)alloc(8192ull * 512 * 2);
  bf16*  Vr   = (bf16*)alloc(8192ull * 512 * 2);

  k_cvt<<<16384, 256, 0, stream>>>(x, xb);
  k_transpose_cvt<<<dim3(32, 32), 256, 0, stream>>>(wq, wqT, 2048, 2048);
  k_transpose_cvt<<<dim3(8, 32),  256, 0, stream>>>(wk, wkT, 2048, 512);
  k_transpose_cvt<<<dim3(8, 32),  256, 0, stream>>>(wv, wvT, 2048, 512);
  k_transpose_cvt<<<dim3(32, 32), 256, 0, stream>>>(wo, woT, 2048, 2048);
  k_rope_tab<<<512, 256, 0, stream>>>(tab);

  k_gemm<1><<<dim3(16, 64), 256, 0, stream>>>(xb, wqT, Qtmp, 8192, 2048, 2048);
  k_gemm<1><<<dim3(4, 64),  256, 0, stream>>>(xb, wkT, Ktmp, 8192, 512, 2048);
  k_gemm<2><<<dim3(4, 64),  256, 0, stream>>>(xb, wvT, Vr,   8192, 512, 2048);

  k_rope<4><<<8192, 256, 0, stream>>>(Qtmp, Qr, tab);  // Q: 16 heads
  k_rope<2><<<2048, 256, 0, stream>>>(Ktmp, Kr, tab);  // K: 4 kv heads

  k_attn<<<dim3(8, 64), 256, 0, stream>>>(Qr, Kr, Vr, Qtmp);

  k_gemm<0><<<dim3(16, 64), 256, 0, stream>>>(Qtmp, woT, d_out, 8192, 2048, 2048);
}

// Round 4
// 367.532 us; speedup vs baseline: 1.7677x; 1.3069x over previous
//
#include <hip/hip_runtime.h>

typedef __bf16 bf16;
typedef float  f32x4  __attribute__((ext_vector_type(4)));
typedef float  f32x2  __attribute__((ext_vector_type(2)));
typedef __bf16 bf16x8 __attribute__((ext_vector_type(8)));
typedef __bf16 bf16x4 __attribute__((ext_vector_type(4)));
typedef unsigned short ushort4_ __attribute__((ext_vector_type(4)));

typedef unsigned int __attribute__((address_space(1))) uint_g;
typedef unsigned int __attribute__((address_space(3))) uint_l;

#define DEV __device__ __forceinline__

DEV void gload16(const void* g, void* l) {
  // async global->LDS, 16B per lane; LDS dst is wave-uniform base + lane*16
  __builtin_amdgcn_global_load_lds((uint_g*)g, (uint_l*)l, 16, 0, 0);
}

#define PHASE_SYNC do { \
  asm volatile("s_barrier" ::: "memory"); \
  asm volatile("s_waitcnt lgkmcnt(0)" ::: "memory"); \
  __builtin_amdgcn_sched_barrier(0); } while (0)

// ---------------- fp32 -> bf16 convert (vectorized) ----------------
__global__ void k_cvt(const float* __restrict__ in, bf16* __restrict__ out) {
  int i = blockIdx.x * 256 + threadIdx.x;          // one float4 per thread
  f32x4 v = *((const f32x4*)in + i);
  bf16x4 o;
  o[0] = (bf16)v[0]; o[1] = (bf16)v[1]; o[2] = (bf16)v[2]; o[3] = (bf16)v[3];
  *((bf16x4*)out + i) = o;
}

// ---------------- [K][N] fp32 -> [N][K] bf16 transpose ----------------
__global__ void k_transpose_cvt(const float* __restrict__ in, bf16* __restrict__ out,
                                int K, int N) {
  __shared__ bf16 tile[64][65];
  int n0 = blockIdx.x * 64, k0 = blockIdx.y * 64;
  int tx = threadIdx.x & 63, ty = threadIdx.x >> 6;
#pragma unroll
  for (int r = 0; r < 64; r += 4)
    tile[r + ty][tx] = (bf16)in[(size_t)(k0 + r + ty) * N + n0 + tx];
  __syncthreads();
#pragma unroll
  for (int r = 0; r < 64; r += 4)
    out[(size_t)(n0 + r + ty) * K + k0 + tx] = tile[tx][r + ty];
}

// ---------------- RoPE cos/sin table: [T][64] of (cos,sin) ----------------
__global__ void k_rope_tab(f32x2* __restrict__ tab) {
  int idx = blockIdx.x * 256 + threadIdx.x;   // T*64
  int t = idx >> 6, i = idx & 63;
  float inv = powf(10000.f, -(float)i * (1.f / 64.f));
  float ang = (float)t * inv;
  f32x2 cs; cs[0] = cosf(ang); cs[1] = sinf(ang);
  tab[idx] = cs;
}

// ---------------- 256x256 deep-pipelined GEMM: C = A @ Bt^T ----------------
// A [M][K] bf16 row-major, Bt [N][K] bf16 row-major. K multiple of 64.
// 8 waves (512 thr), BK=64, double-buffered 128KB LDS, XOR-swizzled (byte ^= (row&7)<<4),
// staged via pre-swizzled global source (rule #21). 4 phases/K-tile, one vmcnt(0) drain
// per K-tile AFTER the last MFMA cluster (stages issued 3 phases earlier).
// MODE 0: C fp32 [M][2048].
// MODE 1: QKV split: bn<8 -> Cq bf16 [M][2048]; bn<10 -> Ck bf16 [M][512];
//         else -> Cv bf16 V-transpose [b][kv][d][t].
template <int MODE>
__global__ __launch_bounds__(512, 2) void k_gemm256(const bf16* __restrict__ A,
                                                    const bf16* __restrict__ Bt,
                                                    void* __restrict__ Cq,
                                                    bf16* __restrict__ Ck,
                                                    bf16* __restrict__ Cv,
                                                    int K) {
  __shared__ bf16 Asm[2][256 * 64];
  __shared__ bf16 Bsm[2][256 * 64];
  const int tid = threadIdx.x;
  const int w = tid >> 6, l = tid & 63, lr = l & 15, lg = l >> 4;
  const int wr = w >> 2, wc = w & 3;
  const int bn = blockIdx.x, bm = blockIdx.y;

  // staging geometry: stmt s covers LDS bytes [s*8192, s*8192+8192), thread -> row/colbyte
  const int srow = tid >> 3;                                    // 0..63
  const int scb = ((tid & 7) << 4) ^ ((srow & 7) << 4);         // pre-swizzled col byte
  const bf16* Ag = A  + ((size_t)(bm * 256) + srow) * K;
  const bf16* Bg = Bt + ((size_t)(bn * 256) + srow) * K;
  const int ldsbase = w << 10;                                  // per-wave 1KB slice

  auto stA = [&](int buf, int s, int k0) {
    gload16((const char*)Ag + ((size_t)(s * 64) * K + k0) * 2 + scb,
            (char*)&Asm[buf][0] + s * 8192 + ldsbase);
  };
  auto stB = [&](int buf, int s, int k0) {
    gload16((const char*)Bg + ((size_t)(s * 64) * K + k0) * 2 + scb,
            (char*)&Bsm[buf][0] + s * 8192 + ldsbase);
  };
  auto ldA = [&](int buf, int mf, int kk) -> bf16x8 {
    int row = wr * 128 + mf * 16 + lr;
    return *(const bf16x8*)((const char*)&Asm[buf][0] + row * 128 +
                            ((kk * 64 + lg * 16) ^ ((lr & 7) << 4)));
  };
  auto ldB = [&](int buf, int nf, int kk) -> bf16x8 {
    int row = wc * 64 + nf * 16 + lr;
    return *(const bf16x8*)((const char*)&Bsm[buf][0] + row * 128 +
                            ((kk * 64 + lg * 16) ^ ((lr & 7) << 4)));
  };

  f32x4 acc[8][4] = {};
  const int nt = K >> 6;

  // prologue: stage tile 0 into buf 0
#pragma unroll
  for (int s = 0; s < 4; s++) { stA(0, s, 0); stB(0, s, 0); }
  asm volatile("s_waitcnt vmcnt(0)" ::: "memory");
  __syncthreads();

#pragma unroll 1
  for (int t = 0; t < nt; t++) {
    const int cur = t & 1, nxt = cur ^ 1;
    const int kn = (t + 1) << 6;
    const bool pre = (t + 1 < nt);
    bf16x8 a0[4][2], a1[4][2], b0[2][2], b1[2][2];

    // ---- phase 0: read A m0-3, B n0-1; stage A0-2(t+1) ----
#pragma unroll
    for (int mf = 0; mf < 4; mf++) { a0[mf][0] = ldA(cur, mf, 0); a0[mf][1] = ldA(cur, mf, 1); }
#pragma unroll
    for (int nf = 0; nf < 2; nf++) { b0[nf][0] = ldB(cur, nf, 0); b0[nf][1] = ldB(cur, nf, 1); }
    if (pre) { stA(nxt, 0, kn); stA(nxt, 1, kn); stA(nxt, 2, kn); }
    PHASE_SYNC;
    __builtin_amdgcn_s_setprio(1);
#pragma unroll
    for (int mf = 0; mf < 4; mf++)
#pragma unroll
      for (int nf = 0; nf < 2; nf++)
#pragma unroll
        for (int kk = 0; kk < 2; kk++)
          acc[mf][nf] = __builtin_amdgcn_mfma_f32_16x16x32_bf16(a0[mf][kk], b0[nf][kk], acc[mf][nf], 0, 0, 0);
    __builtin_amdgcn_s_setprio(0);

    // ---- phase 1: read B n2-3; stage A3,B0,B1(t+1) ----
#pragma unroll
    for (int nf = 0; nf < 2; nf++) { b1[nf][0] = ldB(cur, nf + 2, 0); b1[nf][1] = ldB(cur, nf + 2, 1); }
    if (pre) { stA(nxt, 3, kn); stB(nxt, 0, kn); stB(nxt, 1, kn); }
    PHASE_SYNC;
    __builtin_amdgcn_s_setprio(1);
#pragma unroll
    for (int mf = 0; mf < 4; mf++)
#pragma unroll
      for (int nf = 0; nf < 2; nf++)
#pragma unroll
        for (int kk = 0; kk < 2; kk++)
          acc[mf][nf + 2] = __builtin_amdgcn_mfma_f32_16x16x32_bf16(a0[mf][kk], b1[nf][kk], acc[mf][nf + 2], 0, 0, 0);
    __builtin_amdgcn_s_setprio(0);

    // ---- phase 2: read A m4-7, B n0-1 again; stage B2,B3(t+1) ----
#pragma unroll
    for (int mf = 0; mf < 4; mf++) { a1[mf][0] = ldA(cur, mf + 4, 0); a1[mf][1] = ldA(cur, mf + 4, 1); }
#pragma unroll
    for (int nf = 0; nf < 2; nf++) { b0[nf][0] = ldB(cur, nf, 0); b0[nf][1] = ldB(cur, nf, 1); }
    if (pre) { stB(nxt, 2, kn); stB(nxt, 3, kn); }
    PHASE_SYNC;
    __builtin_amdgcn_s_setprio(1);
#pragma unroll
    for (int mf = 0; mf < 4; mf++)
#pragma unroll
      for (int nf = 0; nf < 2; nf++)
#pragma unroll
        for (int kk = 0; kk < 2; kk++)
          acc[mf + 4][nf] = __builtin_amdgcn_mfma_f32_16x16x32_bf16(a1[mf][kk], b0[nf][kk], acc[mf + 4][nf], 0, 0, 0);
    __builtin_amdgcn_s_setprio(0);

    // ---- phase 3: no reads/stages; drain AFTER the MFMA cluster ----
    __builtin_amdgcn_s_setprio(1);
#pragma unroll
    for (int mf = 0; mf < 4; mf++)
#pragma unroll
      for (int nf = 0; nf < 2; nf++)
#pragma unroll
        for (int kk = 0; kk < 2; kk++)
          acc[mf + 4][nf + 2] = __builtin_amdgcn_mfma_f32_16x16x32_bf16(a1[mf][kk], b1[nf][kk], acc[mf + 4][nf + 2], 0, 0, 0);
    __builtin_amdgcn_s_setprio(0);
    asm volatile("s_waitcnt vmcnt(0)" ::: "memory");
    asm volatile("s_barrier" ::: "memory");
  }

  // ---- epilogue ----
#pragma unroll
  for (int mf = 0; mf < 8; mf++) {
    const int rowb = bm * 256 + wr * 128 + mf * 16 + lg * 4;
#pragma unroll
    for (int nf = 0; nf < 4; nf++) {
      const int col = bn * 256 + wc * 64 + nf * 16 + lr;
      if constexpr (MODE == 0) {
        float* Cf = (float*)Cq;
#pragma unroll
        for (int j = 0; j < 4; j++)
          Cf[(size_t)(rowb + j) * 2048 + col] = acc[mf][nf][j];
      } else {
        if (bn < 8) {
          bf16* Cb = (bf16*)Cq;
#pragma unroll
          for (int j = 0; j < 4; j++)
            Cb[(size_t)(rowb + j) * 2048 + col] = (bf16)acc[mf][nf][j];
        } else if (bn < 10) {
          int kcol = col - 2048;
#pragma unroll
          for (int j = 0; j < 4; j++)
            Ck[(size_t)(rowb + j) * 512 + kcol] = (bf16)acc[mf][nf][j];
        } else {
          int vcol = col - 2560;                 // 0..511
          int kv = vcol >> 7, d = vcol & 127;
          int bb = rowb >> 11, t0 = rowb & 2047;
          size_t off = ((size_t)((bb * 4 + kv) * 128 + d)) * 2048 + t0;
          ushort4_ pk;
#pragma unroll
          for (int j = 0; j < 4; j++)
            pk[j] = __builtin_bit_cast(unsigned short, (bf16)acc[mf][nf][j]);
          *(ushort4_*)(Cv + off) = pk;
        }
      }
    }
  }
}

// ---------------- RoPE + rearrange: [B*T][NH*128] -> [B][NH][T][128] ----------------
template <int LOGNH>
__global__ void k_rope(const bf16* __restrict__ in, bf16* __restrict__ out,
                       const f32x2* __restrict__ tab) {
  const int NH = 1 << LOGNH;
  int idx = blockIdx.x * 256 + threadIdx.x;
  int dq = idx & 15;                        // d0 = dq*4
  int h = (idx >> 4) & (NH - 1);
  int bt = idx >> (4 + LOGNH);
  int t = bt & 2047;
  int d0 = dq * 4;
  const bf16* pin = in + (size_t)bt * (NH * 128) + h * 128;
  bf16x4 x1 = *(const bf16x4*)(pin + d0);
  bf16x4 x2 = *(const bf16x4*)(pin + 64 + d0);
  bf16x4 o1, o2;
#pragma unroll
  for (int j = 0; j < 4; j++) {
    f32x2 cs = tab[t * 64 + d0 + j];
    float a = (float)x1[j], c2 = (float)x2[j];
    o1[j] = (bf16)(a * cs[0] - c2 * cs[1]);
    o2[j] = (bf16)(c2 * cs[0] + a * cs[1]);
  }
  int b = bt >> 11;
  bf16* pout = out + (((size_t)(b << LOGNH) + h) * 2048 + t) * 128;
  *(bf16x4*)(pout + d0) = o1;
  *(bf16x4*)(pout + 64 + d0) = o2;
}

// ---------------- flash attention (causal, GQA), swapped-operand + pipelined ----------------
// Qb [B][16][T][128], Kb [B][4][T][128] (rope'd), Vt [B][4][128][T], AO [B*T][2048]
__global__ __launch_bounds__(256, 2) void k_attn(const bf16* __restrict__ Qb,
                                                 const bf16* __restrict__ Kb,
                                                 const bf16* __restrict__ Vt,
                                                 bf16* __restrict__ AO) {
  __shared__ bf16 Ks[2][64 * 128];  // 32KB, [kv 64][d 128] XOR-swizzled rows
  __shared__ bf16 Vs[128 * 64];     // 16KB, [d 128][kv 64] XOR-swizzled rows
  __shared__ bf16 Ps[4][32 * 64];   // 16KB, per-wave P[qloc 32][kv 64], swizzled
  const int tid = threadIdx.x, w = tid >> 6, l = tid & 63;
  const int bh = blockIdx.y, b = bh >> 4, h = bh & 15, kvh = h >> 2;
  const int pi = blockIdx.x;
  const int lr = l & 15, lg = l >> 4;
  const float cc = 0.08838834764831845f * 1.4426950408889634f;  // scale * log2(e)

  const bf16* Kh = Kb + (size_t)(b * 4 + kvh) * (2048 * 128);
  const bf16* Vh = Vt + (size_t)(b * 4 + kvh) * (128 * 2048);
  char* Pw = (char*)&Ps[w][0];

  auto stageV = [&](int kv0) {
#pragma unroll
    for (int i = 0; i < 4; i++) {
      int vrow = w * 32 + i * 8 + (l >> 3);
      int vcb = ((l & 7) * 16) ^ ((vrow & 7) << 4);
      gload16(Vh + (size_t)vrow * 2048 + kv0 + (vcb >> 1), (bf16*)Vs + w * 2048 + i * 512);
    }
  };
  auto stageK = [&](int kv0, int buf) {
#pragma unroll
    for (int i = 0; i < 4; i++) {
      int krow = w * 16 + i * 4 + lg;
      int kcb = ((l & 15) * 16) ^ ((krow & 7) << 4);
      gload16(Kh + (size_t)(kv0 + krow) * 128 + (kcb >> 1), &Ks[buf][w * 2048 + i * 512]);
    }
  };

#pragma unroll 1
  for (int ph = 0; ph < 2; ph++) {
    const int q0 = (ph ? (15 - pi) : pi) * 128;
    const int nt = q0 / 64 + 2;
    const int qmaxw = q0 + w * 32 + 31;

    bf16x8 qf[2][4];
#pragma unroll
    for (int nq = 0; nq < 2; nq++) {
      const bf16* qp = Qb + (((size_t)(b * 16 + h) * 2048) + q0 + w * 32 + nq * 16 + lr) * 128 + lg * 8;
#pragma unroll
      for (int kk = 0; kk < 4; kk++) qf[nq][kk] = *(const bf16x8*)(qp + kk * 32);
    }

    f32x4 ot[8][2] = {};
    float m_[2] = {-1e30f, -1e30f}, l_[2] = {0.f, 0.f};

    int cur = 0;
    stageK(0, 0);
    __syncthreads();

#pragma unroll 1
    for (int t = 0; t < nt; t++) {
      const int kv0 = t * 64;
      stageV(kv0);
      if (t + 1 < nt) stageK(kv0 + 64, cur ^ 1);
      const bool act = (kv0 <= qmaxw);

      if (act) {
        // S^T = K @ Q^T (raw units): st[nb][nq], rows kv = nb*16+lg*4+j, col q = nq*16+lr
        f32x4 st[4][2] = {};
        __builtin_amdgcn_s_setprio(1);
#pragma unroll
        for (int kk = 0; kk < 4; kk++) {
#pragma unroll
          for (int nb = 0; nb < 4; nb++) {
            int row = nb * 16 + lr;
            const char* p = (const char*)&Ks[cur][0] + row * 256 + ((kk * 64 + lg * 16) ^ ((lr & 7) << 4));
            bf16x8 kf = *(const bf16x8*)p;
#pragma unroll
            for (int nq = 0; nq < 2; nq++)
              st[nb][nq] = __builtin_amdgcn_mfma_f32_16x16x32_bf16(kf, qf[nq][kk], st[nb][nq], 0, 0, 0);
          }
        }
        __builtin_amdgcn_s_setprio(0);

        // mask + per-lane max (raw units)
        const bool needmask = (kv0 + 63 > q0 + w * 32);
        float pv[2][4][4], pmax[2];
#pragma unroll
        for (int nq = 0; nq < 2; nq++) {
          const int qg = q0 + w * 32 + nq * 16 + lr;
          float mx = -1e30f;
#pragma unroll
          for (int nb = 0; nb < 4; nb++)
#pragma unroll
            for (int j = 0; j < 4; j++) {
              float v = st[nb][nq][j];
              if (needmask) {
                int kg = kv0 + nb * 16 + lg * 4 + j;
                if (kg > qg) v = -1e30f;
              }
              pv[nq][nb][j] = v;
              mx = fmaxf(mx, v);
            }
          pmax[nq] = mx;
        }
        // defer-max: only rescale when some row grew past m + 64 (raw; *cc in exp2 domain)
        if (!__all(fmaxf(pmax[0] - m_[0], pmax[1] - m_[1]) <= 64.f)) {
          float corr[2];
#pragma unroll
          for (int nq = 0; nq < 2; nq++) {
            float mx = pmax[nq];
            mx = fmaxf(mx, __shfl_xor(mx, 16));
            mx = fmaxf(mx, __shfl_xor(mx, 32));
            float mnew = fmaxf(m_[nq], mx);
            corr[nq] = exp2f((m_[nq] - mnew) * cc);
            m_[nq] = mnew;
            l_[nq] *= corr[nq];
          }
#pragma unroll
          for (int df = 0; df < 8; df++)
#pragma unroll
            for (int nq = 0; nq < 2; nq++)
              ot[df][nq] *= corr[nq];
        }
        // P = exp2((s - m)*cc), row-sum, P -> per-wave LDS (8B swizzled stores)
#pragma unroll
        for (int nq = 0; nq < 2; nq++) {
          float ls = 0.f;
#pragma unroll
          for (int nb = 0; nb < 4; nb++)
#pragma unroll
            for (int j = 0; j < 4; j++) {
              float pe = exp2f((pv[nq][nb][j] - m_[nq]) * cc);
              pv[nq][nb][j] = pe;
              ls += pe;
            }
          ls += __shfl_xor(ls, 16);
          ls += __shfl_xor(ls, 32);
          l_[nq] += ls;
          const int qloc = nq * 16 + lr;
#pragma unroll
          for (int nb = 0; nb < 4; nb++) {
            ushort4_ pk;
#pragma unroll
            for (int j = 0; j < 4; j++)
              pk[j] = __builtin_bit_cast(unsigned short, (bf16)pv[nq][nb][j]);
            *(ushort4_*)(Pw + qloc * 128 + ((nb * 32 + lg * 8) ^ ((qloc & 7) << 4))) = pk;
          }
        }
      }

      __syncthreads();   // drains vmcnt: V(t) + K(t+1) landed for ALL waves

      if (act) {
        // O^T += V^T @ P^T
        __builtin_amdgcn_s_setprio(1);
#pragma unroll
        for (int s = 0; s < 2; s++) {
          bf16x8 pf[2];
#pragma unroll
          for (int nq = 0; nq < 2; nq++) {
            int qloc = nq * 16 + lr;
            pf[nq] = *(const bf16x8*)(Pw + qloc * 128 + ((s * 64 + lg * 16) ^ ((qloc & 7) << 4)));
          }
#pragma unroll
          for (int df = 0; df < 8; df++) {
            int vrow = df * 16 + lr;
            const char* vp = (const char*)Vs + vrow * 128 + ((s * 64 + lg * 16) ^ ((vrow & 7) << 4));
            bf16x8 vf = *(const bf16x8*)vp;
#pragma unroll
            for (int nq = 0; nq < 2; nq++)
              ot[df][nq] = __builtin_amdgcn_mfma_f32_16x16x32_bf16(vf, pf[nq], ot[df][nq], 0, 0, 0);
          }
        }
        __builtin_amdgcn_s_setprio(0);
      }

      __syncthreads();   // all waves done reading Vs / Ks[cur] before next-iter overwrite
      cur ^= 1;
    }

    // epilogue: O^T / l -> AO[b*T + q][h*128 + d]; factors lane-local
#pragma unroll
    for (int nq = 0; nq < 2; nq++) {
      float inv = 1.f / l_[nq];
      int qg = q0 + w * 32 + nq * 16 + lr;
      bf16* op = AO + ((size_t)b * 2048 + qg) * 2048 + h * 128;
#pragma unroll
      for (int df = 0; df < 8; df++) {
        ushort4_ pk;
#pragma unroll
        for (int j = 0; j < 4; j++)
          pk[j] = __builtin_bit_cast(unsigned short, (bf16)(ot[df][nq][j] * inv));
        *(ushort4_*)(op + df * 16 + lg * 4) = pk;
      }
    }
  }
}

// ---------------- launch ----------------
extern "C" void kernel_launch(void* const* d_in, const int* in_sizes, int n_in,
                              void* d_out, int out_size, void* d_ws, size_t ws_size,
                              hipStream_t stream) {
  const float* x  = (const float*)d_in[0];
  // d_in[1] = additive causal mask: implemented analytically, not read
  const float* wq = (const float*)d_in[2];
  const float* wk = (const float*)d_in[3];
  const float* wv = (const float*)d_in[4];
  const float* wo = (const float*)d_in[5];

  char* p = (char*)d_ws;
  auto alloc = [&](size_t bytes) { char* r = p; p += (bytes + 255) & ~(size_t)255; return r; };
  bf16*  xb     = (bf16*)alloc(8192ull * 2048 * 2);
  bf16*  wqkvT  = (bf16*)alloc(3072ull * 2048 * 2);   // rows: 0-2047 wq^T, 2048-2559 wk^T, 2560-3071 wv^T
  bf16*  woT    = (bf16*)alloc(2048ull * 2048 * 2);
  f32x2* tab    = (f32x2*)alloc(2048ull * 64 * 8);
  bf16*  Qtmp   = (bf16*)alloc(8192ull * 2048 * 2);   // later reused as attention output AO
  bf16*  Ktmp   = (bf16*)alloc(8192ull * 512 * 2);
  bf16*  Qr     = (bf16*)alloc(8192ull * 2048 * 2);
  bf16*  Kr     = (bf16*)alloc(8192ull * 512 * 2);
  bf16*  Vr     = (bf16*)alloc(8192ull * 512 * 2);

  k_cvt<<<16384, 256, 0, stream>>>(x, xb);
  k_transpose_cvt<<<dim3(32, 32), 256, 0, stream>>>(wq, wqkvT, 2048, 2048);
  k_transpose_cvt<<<dim3(8, 32),  256, 0, stream>>>(wk, wqkvT + 2048ull * 2048, 2048, 512);
  k_transpose_cvt<<<dim3(8, 32),  256, 0, stream>>>(wv, wqkvT + 2560ull * 2048, 2048, 512);
  k_transpose_cvt<<<dim3(32, 32), 256, 0, stream>>>(wo, woT, 2048, 2048);
  k_rope_tab<<<512, 256, 0, stream>>>(tab);

  // fused QKV projection: [8192 x 2048] @ [3072 x 2048]^T
  k_gemm256<1><<<dim3(12, 32), 512, 0, stream>>>(xb, wqkvT, Qtmp, Ktmp, Vr, 2048);

  k_rope<4><<<8192, 256, 0, stream>>>(Qtmp, Qr, tab);  // Q: 16 heads
  k_rope<2><<<2048, 256, 0, stream>>>(Ktmp, Kr, tab);  // K: 4 kv heads

  k_attn<<<dim3(8, 64), 256, 0, stream>>>(Qr, Kr, Vr, Qtmp);

  // output projection: [8192 x 2048] @ [2048 x 2048]^T -> fp32
  k_gemm256<0><<<dim3(8, 32), 512, 0, stream>>>(Qtmp, woT, d_out, nullptr, nullptr, 2048);
}